// Round 2
// baseline (1225.395 us; speedup 1.0000x reference)
//
#include <hip/hip_runtime.h>
#include <hip/hip_bf16.h>

#define NEG_SLOPE 0.2f
#define RPW 28  // rows per wave in gemm1

__device__ __forceinline__ float lrelu(float x) {
    return x >= 0.0f ? x : NEG_SLOPE * x;
}

// ---------------- linked-list build (bucket edges by dst) ----------------
__global__ __launch_bounds__(256) void build_list_kernel(
    const int* __restrict__ edst, int* __restrict__ head, int* __restrict__ nxt, int E) {
    int e = blockIdx.x * 256 + threadIdx.x;
    if (e >= E) return;
    int d = edst[e];
    nxt[e] = atomicExch(&head[d], e);
}

// ---------------- GEMM1: h1 = x @ W1 ; as1/ad1 fused -------------------
// 4 k-phases of 128; W1 slice (128x64 f32 = 32KB) staged in LDS per phase.
// Wave processes 4 rows at a time; lane = output column. acc in registers
// across phases so x is read exactly once.
__global__ __launch_bounds__(256) void gemm1_kernel(
    const float* __restrict__ x, const float* __restrict__ W1,
    const float* __restrict__ a_src1, const float* __restrict__ a_dst1,
    float* __restrict__ h1, float* __restrict__ as1, float* __restrict__ ad1, int n) {
    __shared__ float Ws[128 * 64];  // [k][c], straight copy of W1 slice
    const int tid = threadIdx.x;
    const int lane = tid & 63;
    const int gwave = blockIdx.x * 4 + (tid >> 6);
    const int base = gwave * RPW;

    float acc[RPW];
    #pragma unroll
    for (int i = 0; i < RPW; i++) acc[i] = 0.0f;

    for (int p = 0; p < 4; p++) {
        __syncthreads();  // protect previous phase's Ws reads
        #pragma unroll
        for (int it = 0; it < 8; it++) {
            int idx = (tid + it * 256) * 4;
            *(float4*)&Ws[idx] = *(const float4*)&W1[p * 8192 + idx];
        }
        __syncthreads();
        const float* xp = x + p * 128;
        #pragma unroll
        for (int g = 0; g < RPW / 4; g++) {
            int r0 = base + g * 4;
            if (r0 >= n) break;
            int r1 = min(r0 + 1, n - 1);
            int r2 = min(r0 + 2, n - 1);
            int r3 = min(r0 + 3, n - 1);
            const float* x0 = xp + (size_t)r0 * 512;
            const float* x1 = xp + (size_t)r1 * 512;
            const float* x2 = xp + (size_t)r2 * 512;
            const float* x3 = xp + (size_t)r3 * 512;
            float a0 = acc[g * 4 + 0], a1 = acc[g * 4 + 1];
            float a2 = acc[g * 4 + 2], a3 = acc[g * 4 + 3];
            #pragma unroll 4
            for (int k0 = 0; k0 < 128; k0 += 4) {
                float4 v0 = *(const float4*)(x0 + k0);  // wave-uniform broadcast
                float4 v1 = *(const float4*)(x1 + k0);
                float4 v2 = *(const float4*)(x2 + k0);
                float4 v3 = *(const float4*)(x3 + k0);
                float w0 = Ws[(k0 + 0) * 64 + lane];
                float w1 = Ws[(k0 + 1) * 64 + lane];
                float w2 = Ws[(k0 + 2) * 64 + lane];
                float w3 = Ws[(k0 + 3) * 64 + lane];
                a0 = fmaf(v0.x, w0, a0); a0 = fmaf(v0.y, w1, a0);
                a0 = fmaf(v0.z, w2, a0); a0 = fmaf(v0.w, w3, a0);
                a1 = fmaf(v1.x, w0, a1); a1 = fmaf(v1.y, w1, a1);
                a1 = fmaf(v1.z, w2, a1); a1 = fmaf(v1.w, w3, a1);
                a2 = fmaf(v2.x, w0, a2); a2 = fmaf(v2.y, w1, a2);
                a2 = fmaf(v2.z, w2, a2); a2 = fmaf(v2.w, w3, a2);
                a3 = fmaf(v3.x, w0, a3); a3 = fmaf(v3.y, w1, a3);
                a3 = fmaf(v3.z, w2, a3); a3 = fmaf(v3.w, w3, a3);
            }
            acc[g * 4 + 0] = a0; acc[g * 4 + 1] = a1;
            acc[g * 4 + 2] = a2; acc[g * 4 + 3] = a3;
        }
    }
    // epilogue: store h1, fused attention coefficients via 8-lane reduction
    float a_s = a_src1[lane];
    float a_d = a_dst1[lane];
    int hd = lane >> 3, cc = lane & 7;
    for (int i = 0; i < RPW; i++) {
        int row = base + i;
        if (row >= n) break;
        float v = acc[i];
        h1[(size_t)row * 64 + lane] = v;
        float ps = v * a_s;
        float pd = v * a_d;
        #pragma unroll
        for (int off = 1; off < 8; off <<= 1) {
            ps += __shfl_xor(ps, off);
            pd += __shfl_xor(pd, off);
        }
        if (cc == 0) {
            as1[row * 8 + hd] = ps;
            ad1[row * 8 + hd] = pd;
        }
    }
}

// ---------------- layer-1 aggregation: thread per dst node -------------
__global__ __launch_bounds__(256) void agg1_kernel(
    const int* __restrict__ head, const int* __restrict__ nxt, const int* __restrict__ esrc,
    const float* __restrict__ as1, const float* __restrict__ ad1,
    const float* __restrict__ h1, const float* __restrict__ b1,
    float* __restrict__ h2, int n) {
    int d = blockIdx.x * 256 + threadIdx.x;
    if (d >= n) return;
    float ad[8], asl[8];
    {
        float4 t0 = *(const float4*)&ad1[d * 8];
        float4 t1 = *(const float4*)&ad1[d * 8 + 4];
        ad[0] = t0.x; ad[1] = t0.y; ad[2] = t0.z; ad[3] = t0.w;
        ad[4] = t1.x; ad[5] = t1.y; ad[6] = t1.z; ad[7] = t1.w;
        float4 s0 = *(const float4*)&as1[d * 8];
        float4 s1 = *(const float4*)&as1[d * 8 + 4];
        asl[0] = s0.x; asl[1] = s0.y; asl[2] = s0.z; asl[3] = s0.w;
        asl[4] = s1.x; asl[5] = s1.y; asl[6] = s1.z; asl[7] = s1.w;
    }
    float es[8], m[8];
    #pragma unroll
    for (int h = 0; h < 8; h++) { es[h] = lrelu(asl[h] + ad[h]); m[h] = es[h]; }
    // pass 1: segment max
    for (int e = head[d]; e >= 0; e = nxt[e]) {
        int s = esrc[e];
        float4 s0 = *(const float4*)&as1[s * 8];
        float4 s1 = *(const float4*)&as1[s * 8 + 4];
        float av[8] = {s0.x, s0.y, s0.z, s0.w, s1.x, s1.y, s1.z, s1.w};
        #pragma unroll
        for (int h = 0; h < 8; h++) m[h] = fmaxf(m[h], lrelu(av[h] + ad[h]));
    }
    // pass 2: exp-sum + weighted message accumulation
    float denom[8];
    float acc[64];
    {
        float p[8];
        #pragma unroll
        for (int h = 0; h < 8; h++) { p[h] = __expf(es[h] - m[h]); denom[h] = p[h]; }
        const float* hs = h1 + (size_t)d * 64;
        #pragma unroll
        for (int q = 0; q < 16; q++) {
            float4 hv = *(const float4*)(hs + q * 4);
            int b = q * 4, h = q >> 1;
            acc[b + 0] = p[h] * hv.x;
            acc[b + 1] = p[h] * hv.y;
            acc[b + 2] = p[h] * hv.z;
            acc[b + 3] = p[h] * hv.w;
        }
    }
    for (int e = head[d]; e >= 0; e = nxt[e]) {
        int s = esrc[e];
        float4 s0 = *(const float4*)&as1[s * 8];
        float4 s1 = *(const float4*)&as1[s * 8 + 4];
        float av[8] = {s0.x, s0.y, s0.z, s0.w, s1.x, s1.y, s1.z, s1.w};
        float p[8];
        #pragma unroll
        for (int h = 0; h < 8; h++) {
            p[h] = __expf(lrelu(av[h] + ad[h]) - m[h]);
            denom[h] += p[h];
        }
        const float* hs = h1 + (size_t)s * 64;
        #pragma unroll
        for (int q = 0; q < 16; q++) {
            float4 hv = *(const float4*)(hs + q * 4);
            int b = q * 4, h = q >> 1;
            acc[b + 0] = fmaf(p[h], hv.x, acc[b + 0]);
            acc[b + 1] = fmaf(p[h], hv.y, acc[b + 1]);
            acc[b + 2] = fmaf(p[h], hv.z, acc[b + 2]);
            acc[b + 3] = fmaf(p[h], hv.w, acc[b + 3]);
        }
    }
    // epilogue: normalize, +b1, ELU
    #pragma unroll
    for (int j = 0; j < 64; j++) {
        int h = j >> 3;
        float v = acc[j] / denom[h] + b1[j];
        h2[(size_t)d * 64 + j] = v > 0.0f ? v : (__expf(v) - 1.0f);
    }
}

// ---------------- layer-2 linear: g2 = h2 @ W2 ; as2/ad2 ---------------
__global__ __launch_bounds__(256) void lin2_kernel(
    const float* __restrict__ h2, const float* __restrict__ W2,
    const float* __restrict__ a_src2, const float* __restrict__ a_dst2,
    float* __restrict__ g2, float* __restrict__ as2, float* __restrict__ ad2, int n) {
    __shared__ float W2s[64 * 7];
    for (int i = threadIdx.x; i < 64 * 7; i += 256) W2s[i] = W2[i];
    __syncthreads();
    int nd = blockIdx.x * 256 + threadIdx.x;
    if (nd >= n) return;
    const float* hr = h2 + (size_t)nd * 64;
    float g[7] = {0, 0, 0, 0, 0, 0, 0};
    #pragma unroll
    for (int k = 0; k < 64; k += 4) {
        float4 hv = *(const float4*)&hr[k];
        #pragma unroll
        for (int c = 0; c < 7; c++) {
            g[c] = fmaf(hv.x, W2s[(k + 0) * 7 + c], g[c]);
            g[c] = fmaf(hv.y, W2s[(k + 1) * 7 + c], g[c]);
            g[c] = fmaf(hv.z, W2s[(k + 2) * 7 + c], g[c]);
            g[c] = fmaf(hv.w, W2s[(k + 3) * 7 + c], g[c]);
        }
    }
    float s_acc = 0.0f, d_acc = 0.0f;
    #pragma unroll
    for (int c = 0; c < 7; c++) {
        s_acc = fmaf(g[c], a_src2[c], s_acc);
        d_acc = fmaf(g[c], a_dst2[c], d_acc);
        g2[(size_t)nd * 8 + c] = g[c];
    }
    g2[(size_t)nd * 8 + 7] = 0.0f;
    as2[nd] = s_acc;
    ad2[nd] = d_acc;
}

// ---------------- layer-2 aggregation + log_softmax --------------------
__global__ __launch_bounds__(256) void agg2_kernel(
    const int* __restrict__ head, const int* __restrict__ nxt, const int* __restrict__ esrc,
    const float* __restrict__ as2, const float* __restrict__ ad2,
    const float* __restrict__ g2, const float* __restrict__ b2,
    float* __restrict__ out, int n) {
    int d = blockIdx.x * 256 + threadIdx.x;
    if (d >= n) return;
    float adv = ad2[d];
    float es = lrelu(as2[d] + adv);
    float m = es;
    for (int e = head[d]; e >= 0; e = nxt[e]) {
        float t = lrelu(as2[esrc[e]] + adv);
        m = fmaxf(m, t);
    }
    float denom = __expf(es - m);
    float acc[7];
    {
        const float* gs = g2 + (size_t)d * 8;
        float4 g0 = *(const float4*)gs;
        float4 g1 = *(const float4*)(gs + 4);
        acc[0] = denom * g0.x; acc[1] = denom * g0.y; acc[2] = denom * g0.z;
        acc[3] = denom * g0.w; acc[4] = denom * g1.x; acc[5] = denom * g1.y;
        acc[6] = denom * g1.z;
    }
    for (int e = head[d]; e >= 0; e = nxt[e]) {
        int s = esrc[e];
        float p = __expf(lrelu(as2[s] + adv) - m);
        denom += p;
        const float* gs = g2 + (size_t)s * 8;
        float4 g0 = *(const float4*)gs;
        float4 g1 = *(const float4*)(gs + 4);
        acc[0] = fmaf(p, g0.x, acc[0]); acc[1] = fmaf(p, g0.y, acc[1]);
        acc[2] = fmaf(p, g0.z, acc[2]); acc[3] = fmaf(p, g0.w, acc[3]);
        acc[4] = fmaf(p, g1.x, acc[4]); acc[5] = fmaf(p, g1.y, acc[5]);
        acc[6] = fmaf(p, g1.z, acc[6]);
    }
    float o[7];
    float mx = -1e30f;
    #pragma unroll
    for (int c = 0; c < 7; c++) {
        o[c] = acc[c] / denom + b2[c];
        mx = fmaxf(mx, o[c]);
    }
    float sum = 0.0f;
    #pragma unroll
    for (int c = 0; c < 7; c++) sum += __expf(o[c] - mx);
    float lse = mx + __logf(sum);
    #pragma unroll
    for (int c = 0; c < 7; c++) out[(size_t)d * 7 + c] = o[c] - lse;
}

extern "C" void kernel_launch(void* const* d_in, const int* in_sizes, int n_in,
                              void* d_out, int out_size, void* d_ws, size_t ws_size,
                              hipStream_t stream) {
    const float* x      = (const float*)d_in[0];
    const int*   ei     = (const int*)d_in[1];
    const float* W1     = (const float*)d_in[2];
    const float* a_src1 = (const float*)d_in[3];
    const float* a_dst1 = (const float*)d_in[4];
    const float* b1     = (const float*)d_in[5];
    const float* W2     = (const float*)d_in[6];
    const float* a_src2 = (const float*)d_in[7];
    const float* a_dst2 = (const float*)d_in[8];
    const float* b2     = (const float*)d_in[9];

    int N = in_sizes[0] / 512;
    int E = in_sizes[1] / 2;
    const int* esrc = ei;       // edge_index row 0
    const int* edst = ei + E;   // edge_index row 1

    char* ws = (char*)d_ws;
    size_t off = 0;
    auto alloc = [&](size_t bytes) -> void* {
        void* p = ws + off;
        off += (bytes + 255) & ~(size_t)255;
        return p;
    };
    float* h1   = (float*)alloc((size_t)N * 64 * 4);
    float* h2   = (float*)alloc((size_t)N * 64 * 4);
    float* as1  = (float*)alloc((size_t)N * 8 * 4);
    float* ad1  = (float*)alloc((size_t)N * 8 * 4);
    float* g2   = (float*)alloc((size_t)N * 8 * 4);
    float* as2  = (float*)alloc((size_t)N * 4);
    float* ad2  = (float*)alloc((size_t)N * 4);
    int*   head = (int*)alloc((size_t)N * 4);
    int*   nxt  = (int*)alloc((size_t)E * 4);

    hipMemsetAsync(head, 0xFF, (size_t)N * 4, stream);  // head[d] = -1

    int ebl = (E + 255) / 256;
    int nbl = (N + 255) / 256;
    // gemm1: 896 blocks x 4 waves x RPW(28) rows = 100352 >= N
    build_list_kernel<<<ebl, 256, 0, stream>>>(edst, head, nxt, E);
    gemm1_kernel<<<896, 256, 0, stream>>>(x, W1, a_src1, a_dst1, h1, as1, ad1, N);
    agg1_kernel<<<nbl, 256, 0, stream>>>(head, nxt, esrc, as1, ad1, h1, b1, h2, N);
    lin2_kernel<<<nbl, 256, 0, stream>>>(h2, W2, a_src2, a_dst2, g2, as2, ad2, N);
    agg2_kernel<<<nbl, 256, 0, stream>>>(head, nxt, esrc, as2, ad2, g2, b2,
                                         (float*)d_out, N);
}

// Round 3
// 760.256 us; speedup vs baseline: 1.6118x; 1.6118x over previous
//
#include <hip/hip_runtime.h>
#include <hip/hip_bf16.h>

#define NEG_SLOPE 0.2f

typedef __attribute__((ext_vector_type(8))) short bfrag;
typedef __attribute__((ext_vector_type(4))) float f32x4;

__device__ __forceinline__ float lrelu(float x) {
    return x >= 0.0f ? x : NEG_SLOPE * x;
}
__device__ __forceinline__ unsigned short f2bf(float f) {  // round-to-nearest-even
    unsigned int u = __float_as_uint(f);
    u += 0x7fffu + ((u >> 16) & 1u);
    return (unsigned short)(u >> 16);
}
__device__ __forceinline__ float bf2f(unsigned short h) {
    return __uint_as_float(((unsigned int)h) << 16);
}

// ======================= CSR build =======================
__global__ __launch_bounds__(256) void count_kernel(
    const int* __restrict__ edst, int* __restrict__ deg, int E) {
    int e = blockIdx.x * 256 + threadIdx.x;
    if (e < E) atomicAdd(&deg[edst[e]], 1);
}

__global__ __launch_bounds__(256) void scan_a_kernel(
    const int* __restrict__ deg, int* __restrict__ bsum, int n) {
    __shared__ int r[256];
    int t = threadIdx.x;
    int i = blockIdx.x * 256 + t;
    r[t] = (i < n) ? deg[i] : 0;
    __syncthreads();
    for (int off = 128; off > 0; off >>= 1) {
        if (t < off) r[t] += r[t + off];
        __syncthreads();
    }
    if (t == 0) bsum[blockIdx.x] = r[0];
}

__global__ __launch_bounds__(512) void scan_b_kernel(
    const int* __restrict__ bsum, int* __restrict__ boff, int sc) {
    __shared__ int s[512];
    int t = threadIdx.x;
    int v = (t < sc) ? bsum[t] : 0;
    s[t] = v;
    __syncthreads();
    for (int off = 1; off < 512; off <<= 1) {
        int tv = (t >= off) ? s[t - off] : 0;
        __syncthreads();
        s[t] += tv;
        __syncthreads();
    }
    if (t < sc) boff[t] = s[t] - v;  // exclusive
}

__global__ __launch_bounds__(256) void scan_c_kernel(
    const int* __restrict__ deg, const int* __restrict__ boff,
    int* __restrict__ csr_off, int* __restrict__ cursor, int n) {
    __shared__ int s[256];
    int t = threadIdx.x;
    int i = blockIdx.x * 256 + t;
    int v = (i < n) ? deg[i] : 0;
    s[t] = v;
    __syncthreads();
    for (int off = 1; off < 256; off <<= 1) {
        int tv = (t >= off) ? s[t - off] : 0;
        __syncthreads();
        s[t] += tv;
        __syncthreads();
    }
    if (i < n) {
        int o = boff[blockIdx.x] + s[t] - v;
        csr_off[i] = o;
        cursor[i] = o;
    }
}

__global__ __launch_bounds__(256) void scatter_kernel(
    const int* __restrict__ esrc, const int* __restrict__ edst,
    int* __restrict__ cursor, int* __restrict__ col, int E) {
    int e = blockIdx.x * 256 + threadIdx.x;
    if (e >= E) return;
    int p = atomicAdd(&cursor[edst[e]], 1);
    col[p] = esrc[e];
}

// ======================= GEMM1 (MFMA, split-bf16) =======================
// h1 = x(100k x 512) @ W1(512 x 64).  Block = 64 rows, 4 waves x 16 rows.
// K in 4 phases of 128; W phase-slice staged in LDS transposed [n][k],
// split into bf16 hi/lo.  x loaded per-wave from global, split hi/lo.
// acc += xl*wh + xh*wl + xh*wh  (xl*wl negligible) -> ~f32 accuracy.
__global__ __launch_bounds__(256) void gemm1_kernel(
    const float* __restrict__ x, const float* __restrict__ W1,
    float* __restrict__ h1, int n) {
    __shared__ unsigned short Bhi[64 * 136];  // [n][k], stride 136 (16B-aligned, 2-way bank = free)
    __shared__ unsigned short Blo[64 * 136];
    const int tid = threadIdx.x;
    const int lane = tid & 63;
    const int wave = tid >> 6;
    const int l15 = lane & 15;
    const int lq = lane >> 4;           // quad index 0..3
    const int wb = blockIdx.x * 64 + wave * 16;  // wave's first row

    f32x4 acc[4];
    #pragma unroll
    for (int t = 0; t < 4; t++) acc[t] = (f32x4){0.f, 0.f, 0.f, 0.f};

    const int arow = min(wb + l15, n - 1);
    const float* xr = x + (size_t)arow * 512;

    for (int p = 0; p < 4; p++) {
        __syncthreads();
        // stage 128x64 f32 slice -> transposed hi/lo bf16
        #pragma unroll
        for (int i = 0; i < 8; i++) {
            int vidx = tid + i * 256;             // float4 index within slice (2048 total)
            float4 w4 = *(const float4*)&W1[(size_t)p * 8192 + (size_t)vidx * 4];
            int base = vidx * 4;
            int k = base >> 6, c = base & 63;
            float wv[4] = {w4.x, w4.y, w4.z, w4.w};
            #pragma unroll
            for (int q = 0; q < 4; q++) {
                unsigned short hi = f2bf(wv[q]);
                float rem = wv[q] - bf2f(hi);
                Bhi[(c + q) * 136 + k] = hi;
                Blo[(c + q) * 136 + k] = f2bf(rem);
            }
        }
        __syncthreads();

        #pragma unroll
        for (int step = 0; step < 4; step++) {
            int kb = p * 128 + step * 32 + lq * 8;  // global k of this lane's 8 elements
            float4 v0 = *(const float4*)&xr[kb];
            float4 v1 = *(const float4*)&xr[kb + 4];
            float xf[8] = {v0.x, v0.y, v0.z, v0.w, v1.x, v1.y, v1.z, v1.w};
            bfrag ah, al;
            #pragma unroll
            for (int j = 0; j < 8; j++) {
                unsigned short hi = f2bf(xf[j]);
                float rem = xf[j] - bf2f(hi);
                ah[j] = (short)hi;
                al[j] = (short)f2bf(rem);
            }
            int kloc = step * 32 + lq * 8;
            #pragma unroll
            for (int t = 0; t < 4; t++) {
                int nrow = t * 16 + l15;
                bfrag bh = *(const bfrag*)&Bhi[nrow * 136 + kloc];
                bfrag bl = *(const bfrag*)&Blo[nrow * 136 + kloc];
                acc[t] = __builtin_amdgcn_mfma_f32_16x16x32_bf16(al, bh, acc[t], 0, 0, 0);
                acc[t] = __builtin_amdgcn_mfma_f32_16x16x32_bf16(ah, bl, acc[t], 0, 0, 0);
                acc[t] = __builtin_amdgcn_mfma_f32_16x16x32_bf16(ah, bh, acc[t], 0, 0, 0);
            }
        }
    }
    // C/D layout: col = lane&15, row = (lane>>4)*4 + reg
    #pragma unroll
    for (int t = 0; t < 4; t++) {
        #pragma unroll
        for (int reg = 0; reg < 4; reg++) {
            int grow = wb + lq * 4 + reg;
            if (grow < n) h1[(size_t)grow * 64 + t * 16 + l15] = acc[t][reg];
        }
    }
}

// ======================= attention coefficients =======================
// thread per (row, head): as1/ad1 = h1[row, h*8:+8] . a_{src,dst}1[h]
__global__ __launch_bounds__(256) void as_kernel(
    const float* __restrict__ h1, const float* __restrict__ a_src1,
    const float* __restrict__ a_dst1, float* __restrict__ as1,
    float* __restrict__ ad1, int n) {
    int idx = blockIdx.x * 256 + threadIdx.x;
    if (idx >= n * 8) return;
    int h = idx & 7;
    const float* hp = h1 + (size_t)(idx >> 3) * 64 + h * 8;
    float4 h0 = *(const float4*)hp;
    float4 h4 = *(const float4*)(hp + 4);
    float hv[8] = {h0.x, h0.y, h0.z, h0.w, h4.x, h4.y, h4.z, h4.w};
    float s = 0.f, d = 0.f;
    #pragma unroll
    for (int j = 0; j < 8; j++) {
        s = fmaf(hv[j], a_src1[h * 8 + j], s);
        d = fmaf(hv[j], a_dst1[h * 8 + j], d);
    }
    as1[idx] = s;
    ad1[idx] = d;
}

// ======================= agg1 + fused lin2 =======================
// wave per dst node; lane = feature col. Single-pass softmax (scores are
// O(1), no overflow risk; softmax is shift-invariant). Epilogue computes
// h2 = elu(out+b1) in-register, then g2 = h2 @ W2 via 7 wave reductions.
__global__ __launch_bounds__(256) void agg1_kernel(
    const int* __restrict__ csr_off, const int* __restrict__ cursor,
    const int* __restrict__ col, const float* __restrict__ as1,
    const float* __restrict__ ad1, const float* __restrict__ h1,
    const float* __restrict__ b1, const float* __restrict__ W2,
    const float* __restrict__ a_src2, const float* __restrict__ a_dst2,
    float* __restrict__ g2, float* __restrict__ as2, float* __restrict__ ad2,
    int n) {
    int d = blockIdx.x * 4 + (threadIdx.x >> 6);
    if (d >= n) return;
    int c = threadIdx.x & 63;
    int hd = c >> 3;
    float adh = ad1[d * 8 + hd];
    // self-loop
    float p = __expf(lrelu(as1[d * 8 + hd] + adh));
    float denom = p;
    float acc = p * h1[(size_t)d * 64 + c];
    int st = csr_off[d], en = cursor[d];
    for (int e = st; e < en; e++) {
        int s = col[e];
        float ps = __expf(lrelu(as1[s * 8 + hd] + adh));
        denom += ps;
        acc = fmaf(ps, h1[(size_t)s * 64 + c], acc);
    }
    float v = acc / denom + b1[c];
    float h2v = v > 0.f ? v : (__expf(v) - 1.f);  // ELU
    // fused lin2: g[j] = sum_c h2v * W2[c*7+j]
    float g[7];
    #pragma unroll
    for (int j = 0; j < 7; j++) {
        float t = h2v * W2[c * 7 + j];
        #pragma unroll
        for (int off = 1; off < 64; off <<= 1) t += __shfl_xor(t, off);
        g[j] = t;
    }
    float sa = 0.f, da = 0.f;
    #pragma unroll
    for (int j = 0; j < 7; j++) {
        sa = fmaf(g[j], a_src2[j], sa);
        da = fmaf(g[j], a_dst2[j], da);
    }
    if (c < 7) g2[(size_t)d * 8 + c] = g[c];
    if (c == 7) g2[(size_t)d * 8 + 7] = 0.f;
    if (c == 8) as2[d] = sa;
    if (c == 9) ad2[d] = da;
}

// ======================= agg2 + log_softmax =======================
// wave per dst; 8 edges x 8 lanes (lane&7 = class col, col 7 = pad).
__global__ __launch_bounds__(256) void agg2_kernel(
    const int* __restrict__ csr_off, const int* __restrict__ cursor,
    const int* __restrict__ col, const float* __restrict__ as2,
    const float* __restrict__ ad2, const float* __restrict__ g2,
    const float* __restrict__ b2, float* __restrict__ out, int n) {
    int d = blockIdx.x * 4 + (threadIdx.x >> 6);
    if (d >= n) return;
    int lane = threadIdx.x & 63;
    int j = lane >> 3, cc = lane & 7;
    float adv = ad2[d];
    float denom = 0.f, acc = 0.f;
    if (j == 0) {  // self-loop counted once
        float p = __expf(lrelu(as2[d] + adv));
        denom = p;
        acc = p * g2[(size_t)d * 8 + cc];
    }
    int st = csr_off[d], en = cursor[d];
    for (int base = st; base < en; base += 8) {
        int eidx = base + j;
        bool valid = eidx < en;
        int s = valid ? col[eidx] : d;
        float p = valid ? __expf(lrelu(as2[s] + adv)) : 0.f;
        denom += p;
        acc = fmaf(p, g2[(size_t)s * 8 + cc], acc);
    }
    // reduce over the 8 edge-groups (lanes differing in bits 3..5)
    #pragma unroll
    for (int off = 8; off < 64; off <<= 1) {
        acc += __shfl_xor(acc, off);
        denom += __shfl_xor(denom, off);
    }
    float o = acc / denom + ((cc < 7) ? b2[cc] : 0.f);
    // log_softmax across cc=0..6 (reduce over bits 0..2)
    float m = (cc < 7) ? o : -1e30f;
    #pragma unroll
    for (int off = 1; off < 8; off <<= 1) m = fmaxf(m, __shfl_xor(m, off));
    float se = (cc < 7) ? __expf(o - m) : 0.f;
    #pragma unroll
    for (int off = 1; off < 8; off <<= 1) se += __shfl_xor(se, off);
    float lse = m + __logf(se);
    if (j == 0 && cc < 7) out[(size_t)d * 7 + cc] = o - lse;
}

extern "C" void kernel_launch(void* const* d_in, const int* in_sizes, int n_in,
                              void* d_out, int out_size, void* d_ws, size_t ws_size,
                              hipStream_t stream) {
    const float* x      = (const float*)d_in[0];
    const int*   ei     = (const int*)d_in[1];
    const float* W1     = (const float*)d_in[2];
    const float* a_src1 = (const float*)d_in[3];
    const float* a_dst1 = (const float*)d_in[4];
    const float* b1     = (const float*)d_in[5];
    const float* W2     = (const float*)d_in[6];
    const float* a_src2 = (const float*)d_in[7];
    const float* a_dst2 = (const float*)d_in[8];
    const float* b2     = (const float*)d_in[9];

    int N = in_sizes[0] / 512;
    int E = in_sizes[1] / 2;
    const int* esrc = ei;
    const int* edst = ei + E;

    char* ws = (char*)d_ws;
    size_t off = 0;
    auto alloc = [&](size_t bytes) -> void* {
        void* p = ws + off;
        off += (bytes + 255) & ~(size_t)255;
        return p;
    };
    float* h1      = (float*)alloc((size_t)N * 64 * 4);
    float* as1     = (float*)alloc((size_t)N * 8 * 4);
    float* ad1     = (float*)alloc((size_t)N * 8 * 4);
    float* g2      = (float*)alloc((size_t)N * 8 * 4);
    float* as2     = (float*)alloc((size_t)N * 4);
    float* ad2     = (float*)alloc((size_t)N * 4);
    int*   deg     = (int*)alloc((size_t)N * 4);
    int*   csr_off = (int*)alloc((size_t)(N + 1) * 4);
    int*   cursor  = (int*)alloc((size_t)N * 4);
    int*   col     = (int*)alloc((size_t)E * 4);
    int SC = (N + 255) / 256;  // 391
    int*   bsum    = (int*)alloc((size_t)SC * 4);
    int*   boff    = (int*)alloc((size_t)SC * 4);

    hipMemsetAsync(deg, 0, (size_t)N * 4, stream);

    int ebl = (E + 255) / 256;
    int gbl = (N + 63) / 64;       // gemm blocks
    int wbl = (N + 3) / 4;         // wave-per-node blocks

    count_kernel<<<ebl, 256, 0, stream>>>(edst, deg, E);
    scan_a_kernel<<<SC, 256, 0, stream>>>(deg, bsum, N);
    scan_b_kernel<<<1, 512, 0, stream>>>(bsum, boff, SC);
    scan_c_kernel<<<SC, 256, 0, stream>>>(deg, boff, csr_off, cursor, N);
    scatter_kernel<<<ebl, 256, 0, stream>>>(esrc, edst, cursor, col, E);
    gemm1_kernel<<<gbl, 256, 0, stream>>>(x, W1, h1, N);
    as_kernel<<<(N * 8 + 255) / 256, 256, 0, stream>>>(h1, a_src1, a_dst1, as1, ad1, N);
    agg1_kernel<<<wbl, 256, 0, stream>>>(csr_off, cursor, col, as1, ad1, h1, b1,
                                         W2, a_src2, a_dst2, g2, as2, ad2, N);
    agg2_kernel<<<wbl, 256, 0, stream>>>(csr_off, cursor, col, as2, ad2, g2, b2,
                                         (float*)d_out, N);
}

// Round 4
// 630.464 us; speedup vs baseline: 1.9436x; 1.2059x over previous
//
#include <hip/hip_runtime.h>
#include <hip/hip_bf16.h>

#define NEG_SLOPE 0.2f

typedef __attribute__((ext_vector_type(8))) short bfrag;
typedef __attribute__((ext_vector_type(4))) float f32x4;
typedef unsigned short ushort_t;

__device__ __forceinline__ float lrelu(float x) {
    return x >= 0.0f ? x : NEG_SLOPE * x;
}
__device__ __forceinline__ unsigned short f2bf(float f) {  // round-to-nearest-even
    unsigned int u = __float_as_uint(f);
    u += 0x7fffu + ((u >> 16) & 1u);
    return (unsigned short)(u >> 16);
}
__device__ __forceinline__ float bf2f(unsigned short h) {
    return __uint_as_float(((unsigned int)h) << 16);
}
__device__ __forceinline__ float u2lo(unsigned int u) {  // low ushort -> float
    return __uint_as_float(u << 16);
}
__device__ __forceinline__ float u2hi(unsigned int u) {  // high ushort -> float
    return __uint_as_float(u & 0xffff0000u);
}

// ======================= CSR build =======================
__global__ __launch_bounds__(256) void count_kernel(
    const int* __restrict__ edst, int* __restrict__ deg, int E) {
    int e = blockIdx.x * 256 + threadIdx.x;
    if (e < E) atomicAdd(&deg[edst[e]], 1);
}

__global__ __launch_bounds__(256) void scan_a_kernel(
    const int* __restrict__ deg, int* __restrict__ bsum, int n) {
    __shared__ int r[256];
    int t = threadIdx.x;
    int i = blockIdx.x * 256 + t;
    r[t] = (i < n) ? deg[i] : 0;
    __syncthreads();
    for (int off = 128; off > 0; off >>= 1) {
        if (t < off) r[t] += r[t + off];
        __syncthreads();
    }
    if (t == 0) bsum[blockIdx.x] = r[0];
}

__global__ __launch_bounds__(512) void scan_b_kernel(
    const int* __restrict__ bsum, int* __restrict__ boff, int sc) {
    __shared__ int s[512];
    int t = threadIdx.x;
    int v = (t < sc) ? bsum[t] : 0;
    s[t] = v;
    __syncthreads();
    for (int off = 1; off < 512; off <<= 1) {
        int tv = (t >= off) ? s[t - off] : 0;
        __syncthreads();
        s[t] += tv;
        __syncthreads();
    }
    if (t < sc) boff[t] = s[t] - v;  // exclusive
}

__global__ __launch_bounds__(256) void scan_c_kernel(
    const int* __restrict__ deg, const int* __restrict__ boff,
    int* __restrict__ csr_off, int* __restrict__ cursor, int n) {
    __shared__ int s[256];
    int t = threadIdx.x;
    int i = blockIdx.x * 256 + t;
    int v = (i < n) ? deg[i] : 0;
    s[t] = v;
    __syncthreads();
    for (int off = 1; off < 256; off <<= 1) {
        int tv = (t >= off) ? s[t - off] : 0;
        __syncthreads();
        s[t] += tv;
        __syncthreads();
    }
    if (i < n) {
        int o = boff[blockIdx.x] + s[t] - v;
        csr_off[i] = o;
        cursor[i] = o;
    }
}

__global__ __launch_bounds__(256) void scatter_kernel(
    const int* __restrict__ esrc, const int* __restrict__ edst,
    int* __restrict__ cursor, int* __restrict__ col, int E) {
    int e = blockIdx.x * 256 + threadIdx.x;
    if (e >= E) return;
    int p = atomicAdd(&cursor[edst[e]], 1);
    col[p] = esrc[e];
}

// ======================= W1 split-bf16 precompute =======================
// W1T_hi/lo[p][c][kk]: phase-major, transposed, matches gemm1 LDS layout.
__global__ __launch_bounds__(256) void prep_w1_kernel(
    const float* __restrict__ W1, ushort_t* __restrict__ Whi,
    ushort_t* __restrict__ Wlo) {
    int t = blockIdx.x * 256 + threadIdx.x;  // 32768
    int k = t >> 6, c = t & 63;
    float w = W1[t];
    unsigned short hi = f2bf(w);
    float rem = w - bf2f(hi);
    int dst = (k >> 7) * 8192 + c * 128 + (k & 127);
    Whi[dst] = hi;
    Wlo[dst] = f2bf(rem);
}

// ======================= GEMM1 (MFMA, split-bf16) =======================
// h1 = x(N x 512) @ W1(512 x 64), output rows packed bf16 (stride 96 ushorts).
// Block = 64 rows, 4 waves x 16 rows. K in 4 phases of 128.
__global__ __launch_bounds__(256) void gemm1_kernel(
    const float* __restrict__ x, const ushort_t* __restrict__ Whi,
    const ushort_t* __restrict__ Wlo, ushort_t* __restrict__ h1b, int n) {
    __shared__ ushort_t Bhi[64 * 136];  // [c][k], stride 136 (16B-aligned rows)
    __shared__ ushort_t Blo[64 * 136];
    const int tid = threadIdx.x;
    const int lane = tid & 63;
    const int wave = tid >> 6;
    const int l15 = lane & 15;
    const int lq = lane >> 4;
    const int wb = blockIdx.x * 64 + wave * 16;

    f32x4 acc[4];
    #pragma unroll
    for (int t = 0; t < 4; t++) acc[t] = (f32x4){0.f, 0.f, 0.f, 0.f};

    const int arow = min(wb + l15, n - 1);
    const float* xr = x + (size_t)arow * 512;

    for (int p = 0; p < 4; p++) {
        __syncthreads();
        const ushort_t* sh = Whi + p * 8192;
        const ushort_t* sl = Wlo + p * 8192;
        #pragma unroll
        for (int i = 0; i < 4; i++) {
            int lin = (tid + i * 256) * 8;   // 8192 per phase
            int c = lin >> 7, kk = lin & 127;
            *(bfrag*)&Bhi[c * 136 + kk] = *(const bfrag*)&sh[lin];
            *(bfrag*)&Blo[c * 136 + kk] = *(const bfrag*)&sl[lin];
        }
        __syncthreads();

        #pragma unroll
        for (int step = 0; step < 4; step++) {
            int kb = p * 128 + step * 32 + lq * 8;
            float4 v0 = *(const float4*)&xr[kb];
            float4 v1 = *(const float4*)&xr[kb + 4];
            float xf[8] = {v0.x, v0.y, v0.z, v0.w, v1.x, v1.y, v1.z, v1.w};
            bfrag ah, al;
            #pragma unroll
            for (int j = 0; j < 8; j++) {
                unsigned short hi = f2bf(xf[j]);
                float rem = xf[j] - bf2f(hi);
                ah[j] = (short)hi;
                al[j] = (short)f2bf(rem);
            }
            int kloc = step * 32 + lq * 8;
            #pragma unroll
            for (int t = 0; t < 4; t++) {
                int nrow = t * 16 + l15;
                bfrag bh = *(const bfrag*)&Bhi[nrow * 136 + kloc];
                bfrag bl = *(const bfrag*)&Blo[nrow * 136 + kloc];
                acc[t] = __builtin_amdgcn_mfma_f32_16x16x32_bf16(al, bh, acc[t], 0, 0, 0);
                acc[t] = __builtin_amdgcn_mfma_f32_16x16x32_bf16(ah, bl, acc[t], 0, 0, 0);
                acc[t] = __builtin_amdgcn_mfma_f32_16x16x32_bf16(ah, bh, acc[t], 0, 0, 0);
            }
        }
    }
    // C/D: col = lane&15 -> t*16+l15 ; row = lq*4+reg.  Store bf16.
    #pragma unroll
    for (int t = 0; t < 4; t++) {
        #pragma unroll
        for (int reg = 0; reg < 4; reg++) {
            int grow = wb + lq * 4 + reg;
            if (grow < n) h1b[(size_t)grow * 96 + t * 16 + l15] = f2bf(acc[t][reg]);
        }
    }
}

// ======================= attention coefficients =======================
// thread per (row, head); as1 packed into h1b row tail (f32), ad1 separate.
__global__ __launch_bounds__(256) void as_kernel(
    ushort_t* __restrict__ h1b, const float* __restrict__ a_src1,
    const float* __restrict__ a_dst1, float* __restrict__ ad1, int n) {
    int idx = blockIdx.x * 256 + threadIdx.x;
    if (idx >= n * 8) return;
    int h = idx & 7;
    ushort_t* row = h1b + (size_t)(idx >> 3) * 96;
    bfrag hv = *(const bfrag*)&row[h * 8];
    float s = 0.f, d = 0.f;
    #pragma unroll
    for (int j = 0; j < 8; j++) {
        float f = bf2f((unsigned short)hv[j]);
        s = fmaf(f, a_src1[h * 8 + j], s);
        d = fmaf(f, a_dst1[h * 8 + j], d);
    }
    *(float*)(row + 64 + h * 2) = s;  // as1 packed at byte 128+h*4
    ad1[idx] = d;
}

// ======================= agg1 + fused lin2 =======================
// Half-wave (32 lanes) per dst; lane = 2 cols (ushort2). Unroll-2 edge loop
// -> 4 independent gathers in flight per wave. Single-pass softmax.
__global__ __launch_bounds__(256) void agg1_kernel(
    const int* __restrict__ csr_off, const int* __restrict__ cursor,
    const int* __restrict__ col, const ushort_t* __restrict__ h1b,
    const float* __restrict__ ad1, const float* __restrict__ b1,
    const float* __restrict__ W2, const float* __restrict__ a_src2,
    const float* __restrict__ a_dst2, float* __restrict__ g2,
    float* __restrict__ ad2, int n) {
    int d = blockIdx.x * 8 + (threadIdx.x >> 5);
    if (d >= n) return;
    int c = threadIdx.x & 31;   // col-pair index: cols 2c, 2c+1
    int hd = c >> 2;            // head
    const ushort_t* myrow = h1b + (size_t)d * 96;
    float adh = ad1[d * 8 + hd];
    // self-loop
    float asd = *(const float*)(myrow + 64 + hd * 2);
    float p0 = __expf(lrelu(asd + adh));
    unsigned int u = *(const unsigned int*)(myrow + c * 2);
    float denom = p0;
    float acc0 = p0 * u2lo(u);
    float acc1 = p0 * u2hi(u);
    int st = csr_off[d], en = cursor[d];
    int e = st;
    for (; e + 2 <= en; e += 2) {
        int s0 = col[e], s1 = col[e + 1];
        const ushort_t* r0 = h1b + (size_t)s0 * 96;
        const ushort_t* r1 = h1b + (size_t)s1 * 96;
        float a0 = *(const float*)(r0 + 64 + hd * 2);
        float a1 = *(const float*)(r1 + 64 + hd * 2);
        unsigned int u0 = *(const unsigned int*)(r0 + c * 2);
        unsigned int u1 = *(const unsigned int*)(r1 + c * 2);
        float q0 = __expf(lrelu(a0 + adh));
        float q1 = __expf(lrelu(a1 + adh));
        denom += q0 + q1;
        acc0 = fmaf(q0, u2lo(u0), acc0);
        acc1 = fmaf(q0, u2hi(u0), acc1);
        acc0 = fmaf(q1, u2lo(u1), acc0);
        acc1 = fmaf(q1, u2hi(u1), acc1);
    }
    if (e < en) {
        int s0 = col[e];
        const ushort_t* r0 = h1b + (size_t)s0 * 96;
        float a0 = *(const float*)(r0 + 64 + hd * 2);
        unsigned int u0 = *(const unsigned int*)(r0 + c * 2);
        float q0 = __expf(lrelu(a0 + adh));
        denom += q0;
        acc0 = fmaf(q0, u2lo(u0), acc0);
        acc1 = fmaf(q0, u2hi(u0), acc1);
    }
    float v0 = acc0 / denom + b1[2 * c];
    float v1 = acc1 / denom + b1[2 * c + 1];
    float h0 = v0 > 0.f ? v0 : (__expf(v0) - 1.f);
    float h1v = v1 > 0.f ? v1 : (__expf(v1) - 1.f);
    // fused lin2 over the 32-lane half-wave
    float g[7];
    #pragma unroll
    for (int j = 0; j < 7; j++) {
        float t = fmaf(h0, W2[(2 * c) * 7 + j], h1v * W2[(2 * c + 1) * 7 + j]);
        #pragma unroll
        for (int off = 1; off < 32; off <<= 1) t += __shfl_xor(t, off);
        g[j] = t;
    }
    float sa = 0.f, da = 0.f;
    #pragma unroll
    for (int j = 0; j < 7; j++) {
        sa = fmaf(g[j], a_src2[j], sa);
        da = fmaf(g[j], a_dst2[j], da);
    }
    if (c < 7) g2[(size_t)d * 8 + c] = g[c];
    if (c == 7) g2[(size_t)d * 8 + 7] = sa;   // as2 packed in slot 7
    if (c == 8) ad2[d] = da;
}

// ======================= agg2 + log_softmax =======================
// wave per dst; 8 edges x 8 lanes; as2 lives in g2 row slot 7.
__global__ __launch_bounds__(256) void agg2_kernel(
    const int* __restrict__ csr_off, const int* __restrict__ cursor,
    const int* __restrict__ col, const float* __restrict__ ad2,
    const float* __restrict__ g2, const float* __restrict__ b2,
    float* __restrict__ out, int n) {
    int d = blockIdx.x * 4 + (threadIdx.x >> 6);
    if (d >= n) return;
    int lane = threadIdx.x & 63;
    int j = lane >> 3, cc = lane & 7;
    int bl = lane | 7;  // broadcast source lane within 8-group
    float adv = ad2[d];
    // self-loop (counted once: group j==0)
    float vd = g2[(size_t)d * 8 + cc];
    float as2d = __shfl(vd, bl);
    float pd = (j == 0) ? __expf(lrelu(as2d + adv)) : 0.f;
    float denom = pd;
    float acc = pd * vd;
    int st = csr_off[d], en = cursor[d];
    for (int base = st; base < en; base += 8) {
        int eidx = base + j;
        bool valid = eidx < en;
        int s = valid ? col[eidx] : d;
        float val = g2[(size_t)s * 8 + cc];
        float as2s = __shfl(val, bl);
        float p = valid ? __expf(lrelu(as2s + adv)) : 0.f;
        denom += p;
        acc = fmaf(p, val, acc);
    }
    #pragma unroll
    for (int off = 8; off < 64; off <<= 1) {
        acc += __shfl_xor(acc, off);
        denom += __shfl_xor(denom, off);
    }
    float o = acc / denom + ((cc < 7) ? b2[cc] : 0.f);
    float m = (cc < 7) ? o : -1e30f;
    #pragma unroll
    for (int off = 1; off < 8; off <<= 1) m = fmaxf(m, __shfl_xor(m, off));
    float se = (cc < 7) ? __expf(o - m) : 0.f;
    #pragma unroll
    for (int off = 1; off < 8; off <<= 1) se += __shfl_xor(se, off);
    float lse = m + __logf(se);
    if (j == 0 && cc < 7) out[(size_t)d * 7 + cc] = o - lse;
}

extern "C" void kernel_launch(void* const* d_in, const int* in_sizes, int n_in,
                              void* d_out, int out_size, void* d_ws, size_t ws_size,
                              hipStream_t stream) {
    const float* x      = (const float*)d_in[0];
    const int*   ei     = (const int*)d_in[1];
    const float* W1     = (const float*)d_in[2];
    const float* a_src1 = (const float*)d_in[3];
    const float* a_dst1 = (const float*)d_in[4];
    const float* b1     = (const float*)d_in[5];
    const float* W2     = (const float*)d_in[6];
    const float* a_src2 = (const float*)d_in[7];
    const float* a_dst2 = (const float*)d_in[8];
    const float* b2     = (const float*)d_in[9];

    int N = in_sizes[0] / 512;
    int E = in_sizes[1] / 2;
    const int* esrc = ei;
    const int* edst = ei + E;

    char* ws = (char*)d_ws;
    size_t off = 0;
    auto alloc = [&](size_t bytes) -> void* {
        void* p = ws + off;
        off += (bytes + 255) & ~(size_t)255;
        return p;
    };
    ushort_t* h1b  = (ushort_t*)alloc((size_t)N * 96 * 2);  // packed bf16 h + f32 as1
    float* ad1     = (float*)alloc((size_t)N * 8 * 4);
    float* g2      = (float*)alloc((size_t)N * 8 * 4);      // slot 7 = as2
    float* ad2     = (float*)alloc((size_t)N * 4);
    int*   deg     = (int*)alloc((size_t)N * 4);
    int*   csr_off = (int*)alloc((size_t)(N + 1) * 4);
    int*   cursor  = (int*)alloc((size_t)N * 4);
    int*   col     = (int*)alloc((size_t)E * 4);
    ushort_t* Whi  = (ushort_t*)alloc(512 * 64 * 2);
    ushort_t* Wlo  = (ushort_t*)alloc(512 * 64 * 2);
    int SC = (N + 255) / 256;
    int*   bsum    = (int*)alloc((size_t)SC * 4);
    int*   boff    = (int*)alloc((size_t)SC * 4);

    hipMemsetAsync(deg, 0, (size_t)N * 4, stream);

    int ebl = (E + 255) / 256;
    int gbl = (N + 63) / 64;

    count_kernel<<<ebl, 256, 0, stream>>>(edst, deg, E);
    scan_a_kernel<<<SC, 256, 0, stream>>>(deg, bsum, N);
    scan_b_kernel<<<1, 512, 0, stream>>>(bsum, boff, SC);
    scan_c_kernel<<<SC, 256, 0, stream>>>(deg, boff, csr_off, cursor, N);
    scatter_kernel<<<ebl, 256, 0, stream>>>(esrc, edst, cursor, col, E);
    prep_w1_kernel<<<128, 256, 0, stream>>>(W1, Whi, Wlo);
    gemm1_kernel<<<gbl, 256, 0, stream>>>(x, Whi, Wlo, h1b, N);
    as_kernel<<<(N * 8 + 255) / 256, 256, 0, stream>>>(h1b, a_src1, a_dst1, ad1, N);
    agg1_kernel<<<(N + 7) / 8, 256, 0, stream>>>(csr_off, cursor, col, h1b, ad1, b1,
                                                 W2, a_src2, a_dst2, g2, ad2, N);
    agg2_kernel<<<(N + 3) / 4, 256, 0, stream>>>(csr_off, cursor, col, ad2, g2, b2,
                                                 (float*)d_out, N);
}

// Round 5
// 488.282 us; speedup vs baseline: 2.5096x; 1.2912x over previous
//
#include <hip/hip_runtime.h>
#include <hip/hip_bf16.h>

#define NEG_SLOPE 0.2f
#define SB 256          // bucket-scatter workgroups (fused into gemm kernel)
#define HWG 384         // histogram workgroups

typedef __attribute__((ext_vector_type(8))) short bfrag;
typedef __attribute__((ext_vector_type(4))) float f32x4;
typedef unsigned short ushort_t;

__device__ __forceinline__ float lrelu(float x) {
    return x >= 0.0f ? x : NEG_SLOPE * x;
}
__device__ __forceinline__ unsigned short f2bf(float f) {  // round-to-nearest-even
    unsigned int u = __float_as_uint(f);
    u += 0x7fffu + ((u >> 16) & 1u);
    return (unsigned short)(u >> 16);
}
__device__ __forceinline__ float bf2f(unsigned short h) {
    return __uint_as_float(((unsigned int)h) << 16);
}
__device__ __forceinline__ float u2lo(unsigned int u) {
    return __uint_as_float(u << 16);
}
__device__ __forceinline__ float u2hi(unsigned int u) {
    return __uint_as_float(u & 0xffff0000u);
}

// ============ K1: bucket histogram + W1 split-bf16 prep (fused) ============
// blocks [0,128): prep W1 -> transposed hi/lo bf16.  blocks [128,128+HWG): hist.
__global__ __launch_bounds__(256) void hist_prep_kernel(
    const int* __restrict__ edst, int* __restrict__ bcnt, int E, int NB,
    const float* __restrict__ W1, ushort_t* __restrict__ Whi,
    ushort_t* __restrict__ Wlo) {
    if (blockIdx.x < 128) {
        int t = blockIdx.x * 256 + threadIdx.x;  // 32768
        int k = t >> 6, c = t & 63;
        float w = W1[t];
        unsigned short hi = f2bf(w);
        float rem = w - bf2f(hi);
        int dst = (k >> 7) * 8192 + c * 128 + (k & 127);
        Whi[dst] = hi;
        Wlo[dst] = f2bf(rem);
        return;
    }
    __shared__ int hist[512];
    int tid = threadIdx.x;
    for (int i = tid; i < NB; i += 256) hist[i] = 0;
    __syncthreads();
    int wg = blockIdx.x - 128;
    int CH = (E + HWG - 1) / HWG;
    int st = wg * CH, en = min(st + CH, E);
    for (int i = st + tid; i < en; i += 256)
        atomicAdd(&hist[edst[i] >> 8], 1);
    __syncthreads();
    for (int i = tid; i < NB; i += 256)
        if (hist[i] > 0) atomicAdd(&bcnt[i], hist[i]);
}

// ============ K2: bucket exclusive scan (one WG) ============
__global__ __launch_bounds__(512) void bscan_kernel(
    const int* __restrict__ bcnt, int* __restrict__ boff, int* __restrict__ bcur,
    int* __restrict__ csr_off, int NB, int N, int E) {
    __shared__ int s[512];
    int t = threadIdx.x;
    int v = (t < NB) ? bcnt[t] : 0;
    s[t] = v;
    __syncthreads();
    for (int off = 1; off < 512; off <<= 1) {
        int tv = (t >= off) ? s[t - off] : 0;
        __syncthreads();
        s[t] += tv;
        __syncthreads();
    }
    if (t < NB) {
        int o = s[t] - v;
        boff[t] = o;
        bcur[t] = o;
    }
    if (t == 0) {
        boff[NB] = E;
        csr_off[N] = E;
    }
}

// ============ K3: fused GEMM1 + bucket scatter ============
// blocks [0,SB): scatter edges into bucket-contiguous ebuf (int2 {src,dst}).
// blocks [SB, SB+gbl): MFMA gemm h1 = x @ W1 (split-bf16), packed bf16 rows.
__global__ __launch_bounds__(256) void gemm_bscatter_kernel(
    const float* __restrict__ x, const ushort_t* __restrict__ Whi,
    const ushort_t* __restrict__ Wlo, ushort_t* __restrict__ h1b, int n,
    const int* __restrict__ esrc, const int* __restrict__ edst,
    int* __restrict__ bcur, int2* __restrict__ ebuf, int E, int NB) {
    __shared__ __align__(16) ushort_t Bhi[64 * 136];
    __shared__ __align__(16) ushort_t Blo[64 * 136];
    const int tid = threadIdx.x;

    if (blockIdx.x < SB) {
        // ---- bucket scatter ----
        int* hist = (int*)Bhi;
        int* base = hist + 512;
        int* rank = hist + 1024;
        for (int i = tid; i < NB; i += 256) { hist[i] = 0; rank[i] = 0; }
        __syncthreads();
        int CH = (E + SB - 1) / SB;
        int st = blockIdx.x * CH, en = min(st + CH, E);
        for (int i = st + tid; i < en; i += 256)
            atomicAdd(&hist[edst[i] >> 8], 1);
        __syncthreads();
        for (int b = tid; b < NB; b += 256)
            if (hist[b] > 0) base[b] = atomicAdd(&bcur[b], hist[b]);
        __syncthreads();
        for (int i = st + tid; i < en; i += 256) {
            int d = edst[i], s = esrc[i];
            int b = d >> 8;
            int r = atomicAdd(&rank[b], 1);
            ebuf[base[b] + r] = make_int2(s, d);
        }
        return;
    }

    // ---- gemm ----
    const int lane = tid & 63;
    const int wave = tid >> 6;
    const int l15 = lane & 15;
    const int lq = lane >> 4;
    const int wb = (blockIdx.x - SB) * 64 + wave * 16;

    f32x4 acc[4];
    #pragma unroll
    for (int t = 0; t < 4; t++) acc[t] = (f32x4){0.f, 0.f, 0.f, 0.f};

    const int arow = min(wb + l15, n - 1);
    const float* xr = x + (size_t)arow * 512;

    for (int p = 0; p < 4; p++) {
        __syncthreads();
        const ushort_t* sh = Whi + p * 8192;
        const ushort_t* sl = Wlo + p * 8192;
        #pragma unroll
        for (int i = 0; i < 4; i++) {
            int lin = (tid + i * 256) * 8;
            int c = lin >> 7, kk = lin & 127;
            *(bfrag*)&Bhi[c * 136 + kk] = *(const bfrag*)&sh[lin];
            *(bfrag*)&Blo[c * 136 + kk] = *(const bfrag*)&sl[lin];
        }
        __syncthreads();

        #pragma unroll
        for (int step = 0; step < 4; step++) {
            int kb = p * 128 + step * 32 + lq * 8;
            float4 v0 = *(const float4*)&xr[kb];
            float4 v1 = *(const float4*)&xr[kb + 4];
            float xf[8] = {v0.x, v0.y, v0.z, v0.w, v1.x, v1.y, v1.z, v1.w};
            bfrag ah, al;
            #pragma unroll
            for (int j = 0; j < 8; j++) {
                unsigned short hi = f2bf(xf[j]);
                float rem = xf[j] - bf2f(hi);
                ah[j] = (short)hi;
                al[j] = (short)f2bf(rem);
            }
            int kloc = step * 32 + lq * 8;
            #pragma unroll
            for (int t = 0; t < 4; t++) {
                int nrow = t * 16 + l15;
                bfrag bh = *(const bfrag*)&Bhi[nrow * 136 + kloc];
                bfrag bl = *(const bfrag*)&Blo[nrow * 136 + kloc];
                acc[t] = __builtin_amdgcn_mfma_f32_16x16x32_bf16(al, bh, acc[t], 0, 0, 0);
                acc[t] = __builtin_amdgcn_mfma_f32_16x16x32_bf16(ah, bl, acc[t], 0, 0, 0);
                acc[t] = __builtin_amdgcn_mfma_f32_16x16x32_bf16(ah, bh, acc[t], 0, 0, 0);
            }
        }
    }
    #pragma unroll
    for (int t = 0; t < 4; t++) {
        #pragma unroll
        for (int reg = 0; reg < 4; reg++) {
            int grow = wb + lq * 4 + reg;
            if (grow < n) h1b[(size_t)grow * 96 + t * 16 + l15] = f2bf(acc[t][reg]);
        }
    }
}

// ============ K4: per-bucket CSR finalize + attention coeffs (fused) ============
// blocks [0,NB): bucket b -> count dsts in LDS, scan, write csr_off coalesced,
// scatter col within the bucket's private region (L2-resident).
// blocks [NB,...): as_kernel body (as1 packed into h1b tail, ad1 separate).
__global__ __launch_bounds__(256) void finalize_as_kernel(
    const int* __restrict__ boff, const int2* __restrict__ ebuf,
    int* __restrict__ csr_off, int* __restrict__ col, int N, int NB,
    ushort_t* __restrict__ h1b, const float* __restrict__ a_src1,
    const float* __restrict__ a_dst1, float* __restrict__ ad1) {
    int tid = threadIdx.x;
    if ((int)blockIdx.x < NB) {
        int b = blockIdx.x;
        __shared__ int cnt[256];
        __shared__ int cur[256];
        __shared__ int sc[256];
        cnt[tid] = 0;
        __syncthreads();
        int st = boff[b], en = boff[b + 1];
        for (int i = st + tid; i < en; i += 256)
            atomicAdd(&cnt[ebuf[i].y & 255], 1);
        __syncthreads();
        int v = cnt[tid];
        sc[tid] = v;
        __syncthreads();
        for (int off = 1; off < 256; off <<= 1) {
            int tv = (tid >= off) ? sc[tid - off] : 0;
            __syncthreads();
            sc[tid] += tv;
            __syncthreads();
        }
        int dbase = b << 8;
        int nd = min(256, N - dbase);
        int o = st + sc[tid] - v;   // exclusive
        if (tid < nd) {
            csr_off[dbase + tid] = o;
            cur[tid] = o;
        }
        __syncthreads();
        for (int i = st + tid; i < en; i += 256) {
            int2 p = ebuf[i];
            int r = atomicAdd(&cur[p.y & 255], 1);
            col[r] = p.x;
        }
        return;
    }
    // ---- attention coefficients ----
    int idx = ((int)blockIdx.x - NB) * 256 + tid;
    if (idx >= N * 8) return;
    int h = idx & 7;
    ushort_t* row = h1b + (size_t)(idx >> 3) * 96;
    bfrag hv = *(const bfrag*)&row[h * 8];
    float s = 0.f, d = 0.f;
    #pragma unroll
    for (int j = 0; j < 8; j++) {
        float f = bf2f((unsigned short)hv[j]);
        s = fmaf(f, a_src1[h * 8 + j], s);
        d = fmaf(f, a_dst1[h * 8 + j], d);
    }
    *(float*)(row + 64 + h * 2) = s;
    ad1[idx] = d;
}

// ============ agg1 + fused lin2 ============
__global__ __launch_bounds__(256) void agg1_kernel(
    const int* __restrict__ csr_off, const int* __restrict__ col,
    const ushort_t* __restrict__ h1b, const float* __restrict__ ad1,
    const float* __restrict__ b1, const float* __restrict__ W2,
    const float* __restrict__ a_src2, const float* __restrict__ a_dst2,
    float* __restrict__ g2, float* __restrict__ ad2, int n) {
    int d = blockIdx.x * 8 + (threadIdx.x >> 5);
    if (d >= n) return;
    int c = threadIdx.x & 31;
    int hd = c >> 2;
    const ushort_t* myrow = h1b + (size_t)d * 96;
    float adh = ad1[d * 8 + hd];
    float asd = *(const float*)(myrow + 64 + hd * 2);
    float p0 = __expf(lrelu(asd + adh));
    unsigned int u = *(const unsigned int*)(myrow + c * 2);
    float denom = p0;
    float acc0 = p0 * u2lo(u);
    float acc1 = p0 * u2hi(u);
    int st = csr_off[d], en = csr_off[d + 1];
    int e = st;
    for (; e + 2 <= en; e += 2) {
        int s0 = col[e], s1 = col[e + 1];
        const ushort_t* r0 = h1b + (size_t)s0 * 96;
        const ushort_t* r1 = h1b + (size_t)s1 * 96;
        float a0 = *(const float*)(r0 + 64 + hd * 2);
        float a1 = *(const float*)(r1 + 64 + hd * 2);
        unsigned int u0 = *(const unsigned int*)(r0 + c * 2);
        unsigned int u1 = *(const unsigned int*)(r1 + c * 2);
        float q0 = __expf(lrelu(a0 + adh));
        float q1 = __expf(lrelu(a1 + adh));
        denom += q0 + q1;
        acc0 = fmaf(q0, u2lo(u0), acc0);
        acc1 = fmaf(q0, u2hi(u0), acc1);
        acc0 = fmaf(q1, u2lo(u1), acc0);
        acc1 = fmaf(q1, u2hi(u1), acc1);
    }
    if (e < en) {
        int s0 = col[e];
        const ushort_t* r0 = h1b + (size_t)s0 * 96;
        float a0 = *(const float*)(r0 + 64 + hd * 2);
        unsigned int u0 = *(const unsigned int*)(r0 + c * 2);
        float q0 = __expf(lrelu(a0 + adh));
        denom += q0;
        acc0 = fmaf(q0, u2lo(u0), acc0);
        acc1 = fmaf(q0, u2hi(u0), acc1);
    }
    float v0 = acc0 / denom + b1[2 * c];
    float v1 = acc1 / denom + b1[2 * c + 1];
    float h0 = v0 > 0.f ? v0 : (__expf(v0) - 1.f);
    float h1v = v1 > 0.f ? v1 : (__expf(v1) - 1.f);
    float g[7];
    #pragma unroll
    for (int j = 0; j < 7; j++) {
        float t = fmaf(h0, W2[(2 * c) * 7 + j], h1v * W2[(2 * c + 1) * 7 + j]);
        #pragma unroll
        for (int off = 1; off < 32; off <<= 1) t += __shfl_xor(t, off);
        g[j] = t;
    }
    float sa = 0.f, da = 0.f;
    #pragma unroll
    for (int j = 0; j < 7; j++) {
        sa = fmaf(g[j], a_src2[j], sa);
        da = fmaf(g[j], a_dst2[j], da);
    }
    if (c < 7) g2[(size_t)d * 8 + c] = g[c];
    if (c == 7) g2[(size_t)d * 8 + 7] = sa;
    if (c == 8) ad2[d] = da;
}

// ============ agg2 + log_softmax ============
__global__ __launch_bounds__(256) void agg2_kernel(
    const int* __restrict__ csr_off, const int* __restrict__ col,
    const float* __restrict__ ad2, const float* __restrict__ g2,
    const float* __restrict__ b2, float* __restrict__ out, int n) {
    int d = blockIdx.x * 4 + (threadIdx.x >> 6);
    if (d >= n) return;
    int lane = threadIdx.x & 63;
    int j = lane >> 3, cc = lane & 7;
    int bl = lane | 7;
    float adv = ad2[d];
    float vd = g2[(size_t)d * 8 + cc];
    float as2d = __shfl(vd, bl);
    float pd = (j == 0) ? __expf(lrelu(as2d + adv)) : 0.f;
    float denom = pd;
    float acc = pd * vd;
    int st = csr_off[d], en = csr_off[d + 1];
    for (int base = st; base < en; base += 8) {
        int eidx = base + j;
        bool valid = eidx < en;
        int s = valid ? col[eidx] : d;
        float val = g2[(size_t)s * 8 + cc];
        float as2s = __shfl(val, bl);
        float p = valid ? __expf(lrelu(as2s + adv)) : 0.f;
        denom += p;
        acc = fmaf(p, val, acc);
    }
    #pragma unroll
    for (int off = 8; off < 64; off <<= 1) {
        acc += __shfl_xor(acc, off);
        denom += __shfl_xor(denom, off);
    }
    float o = acc / denom + ((cc < 7) ? b2[cc] : 0.f);
    float m = (cc < 7) ? o : -1e30f;
    #pragma unroll
    for (int off = 1; off < 8; off <<= 1) m = fmaxf(m, __shfl_xor(m, off));
    float se = (cc < 7) ? __expf(o - m) : 0.f;
    #pragma unroll
    for (int off = 1; off < 8; off <<= 1) se += __shfl_xor(se, off);
    float lse = m + __logf(se);
    if (j == 0 && cc < 7) out[(size_t)d * 7 + cc] = o - lse;
}

extern "C" void kernel_launch(void* const* d_in, const int* in_sizes, int n_in,
                              void* d_out, int out_size, void* d_ws, size_t ws_size,
                              hipStream_t stream) {
    const float* x      = (const float*)d_in[0];
    const int*   ei     = (const int*)d_in[1];
    const float* W1     = (const float*)d_in[2];
    const float* a_src1 = (const float*)d_in[3];
    const float* a_dst1 = (const float*)d_in[4];
    const float* b1     = (const float*)d_in[5];
    const float* W2     = (const float*)d_in[6];
    const float* a_src2 = (const float*)d_in[7];
    const float* a_dst2 = (const float*)d_in[8];
    const float* b2     = (const float*)d_in[9];

    int N = in_sizes[0] / 512;
    int E = in_sizes[1] / 2;
    const int* esrc = ei;
    const int* edst = ei + E;
    int NB = (N + 255) >> 8;   // 391 dst-buckets of 256 nodes

    char* ws = (char*)d_ws;
    size_t off = 0;
    auto alloc = [&](size_t bytes) -> void* {
        void* p = ws + off;
        off += (bytes + 255) & ~(size_t)255;
        return p;
    };
    ushort_t* h1b  = (ushort_t*)alloc((size_t)N * 96 * 2);
    float* ad1     = (float*)alloc((size_t)N * 8 * 4);
    float* g2      = (float*)alloc((size_t)N * 8 * 4);
    float* ad2     = (float*)alloc((size_t)N * 4);
    int*   csr_off = (int*)alloc((size_t)(N + 1) * 4);
    int*   col     = (int*)alloc((size_t)E * 4);
    int2*  ebuf    = (int2*)alloc((size_t)E * 8);
    ushort_t* Whi  = (ushort_t*)alloc(512 * 64 * 2);
    ushort_t* Wlo  = (ushort_t*)alloc(512 * 64 * 2);
    int*   bcnt    = (int*)alloc((size_t)NB * 4);
    int*   boff    = (int*)alloc((size_t)(NB + 1) * 4);
    int*   bcur    = (int*)alloc((size_t)NB * 4);

    hipMemsetAsync(bcnt, 0, (size_t)NB * 4, stream);

    int gbl = (N + 63) / 64;
    int abl = (N * 8 + 255) / 256;

    hist_prep_kernel<<<128 + HWG, 256, 0, stream>>>(edst, bcnt, E, NB, W1, Whi, Wlo);
    bscan_kernel<<<1, 512, 0, stream>>>(bcnt, boff, bcur, csr_off, NB, N, E);
    gemm_bscatter_kernel<<<SB + gbl, 256, 0, stream>>>(x, Whi, Wlo, h1b, N,
                                                       esrc, edst, bcur, ebuf, E, NB);
    finalize_as_kernel<<<NB + abl, 256, 0, stream>>>(boff, ebuf, csr_off, col, N, NB,
                                                     h1b, a_src1, a_dst1, ad1);
    agg1_kernel<<<(N + 7) / 8, 256, 0, stream>>>(csr_off, col, h1b, ad1, b1,
                                                 W2, a_src2, a_dst2, g2, ad2, N);
    agg2_kernel<<<(N + 3) / 4, 256, 0, stream>>>(csr_off, col, ad2, g2, b2,
                                                 (float*)d_out, N);
}